// Round 2
// baseline (250.729 us; speedup 1.0000x reference)
//
#include <hip/hip_runtime.h>
#include <hip/hip_bf16.h>

// Causal SDPA: B=4, H=16, S=2048, D=64, fp32 in/out.
// R10 = barrier-free flash. Evidence: R8->R9 halved per-wave LDS+VALU work at
// halved occupancy and wall time was invariant => latency/lockstep-bound, not
// pipe-bound. So this round removes the lockstep:
//   (1) K/V fragments are read DIRECTLY from L2 into registers (Kh/Vt are f16,
//       pre-transposed, XCD-pinned: 8 bh x 512KB = 4MB = one XCD L2). No K/V
//       LDS staging, no global_load_lds DMA, and NO __syncthreads in the
//       k-loop at all.
//   (2) One wave per block (64 thr), 32 q-rows per wave; P roundtrip stays in
//       wave-private LDS (4KB) ordered by same-wave lgkmcnt only. Grid =
//       64 bh x 32 balanced causal pairs (t, 63-t) = 2048 blocks = 8
//       free-running waves/CU.
//   (3) Diagonal tile peeled: even-t tiles compute only the live half
//       (CN=2/SN=1), odd-t full with mask.
// Fragment math (MFMA layouts, P swizzle, ones-MFMA l-sum, epilogue) is
// identical to the harness-verified R8/R9.

#define SEQ 2048
#define DIM 64
#define BH  64

typedef _Float16 half8  __attribute__((ext_vector_type(8)));
typedef _Float16 half4v __attribute__((ext_vector_type(4)));
typedef float    float4v __attribute__((ext_vector_type(4)));

#if defined(__has_builtin)
#if __has_builtin(__builtin_elementwise_min)
#define EMIN4(a, b) __builtin_elementwise_min((a), (b))
#endif
#endif
#ifndef EMIN4
__device__ __forceinline__ half4v emin4_fallback(half4v a, half4v b) {
    half4v r;
    r[0] = a[0] < b[0] ? a[0] : b[0];
    r[1] = a[1] < b[1] ? a[1] : b[1];
    r[2] = a[2] < b[2] ? a[2] : b[2];
    r[3] = a[3] < b[3] ? a[3] : b[3];
    return r;
}
#define EMIN4(a, b) emin4_fallback((a), (b))
#endif

// ---------------- pre-pass: K convert + V transpose-convert ----------------
__global__ __launch_bounds__(256)
void prep_kernel(const float* __restrict__ K, const float* __restrict__ V,
                 _Float16* __restrict__ Kh, _Float16* __restrict__ Vt) {
    const int bid = blockIdx.x;
    const int tid = threadIdx.x;
    if (bid < 4096) {
        // K: fp32 -> f16, same layout, fully coalesced.
        size_t idx = (size_t)bid * 2048 + (size_t)tid * 8;
        float4v a = *(const float4v*)(K + idx);
        float4v b = *(const float4v*)(K + idx + 4);
        half8 h;
        h[0] = (_Float16)a[0]; h[1] = (_Float16)a[1];
        h[2] = (_Float16)a[2]; h[3] = (_Float16)a[3];
        h[4] = (_Float16)b[0]; h[5] = (_Float16)b[1];
        h[6] = (_Float16)b[2]; h[7] = (_Float16)b[3];
        *(half8*)(Kh + idx) = h;
    } else {
        // V transpose via LDS, flat [64 rows x 8 chunks of 16B].
        // Chunk c of row r stored at c ^ k(r), k(r) = (r + (r>>3)) & 7.
        __shared__ _Float16 Vl[64 * 64];
        const int b  = bid - 4096;
        const int bh = b >> 5;
        const int s0 = (b & 31) * 64;
        {
            const int r   = tid >> 2;         // s within tile
            const int c16 = (tid & 3) * 16;   // col group (d)
            const float* p = V + ((size_t)bh * SEQ + s0 + r) * DIM + c16;
            float4v x0 = *(const float4v*)(p);
            float4v x1 = *(const float4v*)(p + 4);
            float4v x2 = *(const float4v*)(p + 8);
            float4v x3 = *(const float4v*)(p + 12);
            half8 h0, h1;
            h0[0] = (_Float16)x0[0]; h0[1] = (_Float16)x0[1];
            h0[2] = (_Float16)x0[2]; h0[3] = (_Float16)x0[3];
            h0[4] = (_Float16)x1[0]; h0[5] = (_Float16)x1[1];
            h0[6] = (_Float16)x1[2]; h0[7] = (_Float16)x1[3];
            h1[0] = (_Float16)x2[0]; h1[1] = (_Float16)x2[1];
            h1[2] = (_Float16)x2[2]; h1[3] = (_Float16)x2[3];
            h1[4] = (_Float16)x3[0]; h1[5] = (_Float16)x3[1];
            h1[6] = (_Float16)x3[2]; h1[7] = (_Float16)x3[3];
            const int k  = (r + (r >> 3)) & 7;
            const int j0 = c16 >> 3;          // 0,2,4,6
            *(half8*)&Vl[r * 64 + ((j0    ) ^ k) * 8] = h0;
            *(half8*)&Vl[r * 64 + ((j0 + 1) ^ k) * 8] = h1;
        }
        __syncthreads();
        {
            const int d  = tid >> 2;          // output row (d)
            const int sc = (tid & 3) * 16;    // s chunk
            const int dh = d >> 3;            // chunk index of col d
            const int dl = d & 7;             // offset within chunk
            half8 o0, o1;
#pragma unroll
            for (int j = 0; j < 8; ++j) {
                const int s1 = sc + j;
                const int s2 = sc + 8 + j;
                o0[j] = Vl[s1 * 64 + ((dh ^ ((s1 + (s1 >> 3)) & 7)) << 3) + dl];
                o1[j] = Vl[s2 * 64 + ((dh ^ ((s2 + (s2 >> 3)) & 7)) << 3) + dl];
            }
            _Float16* op = Vt + ((size_t)bh * DIM + d) * SEQ + s0 + sc;
            *(half8*)op       = o0;
            *(half8*)(op + 8) = o1;
        }
    }
}

// ---------------- per-KV-tile body (shared by main loop and peeled diag) ----
// CN: live kv 16-blocks (S^T rows). SN: live kv 32-slices for PV.
// MASK: apply causal mask (diagonal tile only).
template<int CN, int SN, bool MASK>
__device__ __forceinline__ void kv_tile(
    const _Float16* __restrict__ Kt,    // Kb + kt*64*DIM
    const _Float16* __restrict__ Vt0,   // Vb + kt*64
    int kvbase, int q0, int row, int quad,
    const half8 (&qf)[4],
    float4v (&o_acc)[2][4],
    float4v (&lacc)[2],
    _Float16* __restrict__ Pl,
    const half8& ones)
{
    const float4v z0 = {0.f, 0.f, 0.f, 0.f};

    // ---- K fragments direct from L2 (A-operand rows kv = c*16+row)
    half8 kfr[CN][2];
#pragma unroll
    for (int c = 0; c < CN; ++c) {
        const _Float16* kp = Kt + (size_t)(c * 16 + row) * DIM + quad * 8;
        kfr[c][0] = *(const half8*)(kp);
        kfr[c][1] = *(const half8*)(kp + 32);
    }
    // ---- V fragments direct from L2 (A-operand rows d = c*16+row); used
    //      only after softmax -> L2 latency hidden under S^T + exp2.
    half8 vfr[4][SN];
#pragma unroll
    for (int c = 0; c < 4; ++c) {
        const _Float16* vp = Vt0 + (size_t)(c * 16 + row) * SEQ + quad * 8;
#pragma unroll
        for (int s = 0; s < SN; ++s)
            vfr[c][s] = *(const half8*)(vp + s * 32);
    }

    // ---- S^T = K * Q^T  (D: row = kv, col = q)
    float4v sacc[2][CN];
#pragma unroll
    for (int c = 0; c < CN; ++c)
#pragma unroll
        for (int qs = 0; qs < 2; ++qs) {
            float4v s0 = __builtin_amdgcn_mfma_f32_16x16x32_f16(kfr[c][0], qf[qs * 2 + 0], z0, 0, 0, 0);
            sacc[qs][c] = __builtin_amdgcn_mfma_f32_16x16x32_f16(kfr[c][1], qf[qs * 2 + 1], s0, 0, 0, 0);
        }

    // ---- exp2 + pack + P write, fused per (qs,c) (short f32 live ranges)
    half4v wcap;
#pragma unroll
    for (int j = 0; j < 4; ++j) wcap[j] = (_Float16)16384.0f;   // 2^14
#pragma unroll
    for (int qs = 0; qs < 2; ++qs) {
        const int ql = q0 + qs * 16 + row;
#pragma unroll
        for (int c = 0; c < CN; ++c) {
            float p[4];
#pragma unroll
            for (int r = 0; r < 4; ++r) {
                float sx = sacc[qs][c][r];
                if (MASK) {
                    const int kv = kvbase + c * 16 + quad * 4 + r;
                    sx = (kv > ql) ? -1e30f : sx;
                }
                p[r] = exp2f(sx);
            }
#if defined(__has_builtin) && __has_builtin(__builtin_amdgcn_cvt_pkrtz)
            auto t0 = __builtin_amdgcn_cvt_pkrtz(p[0], p[1]);
            auto t1 = __builtin_amdgcn_cvt_pkrtz(p[2], p[3]);
            half4v w;
            w[0] = t0[0]; w[1] = t0[1]; w[2] = t1[0]; w[3] = t1[1];
#else
            half4v w;
            w[0] = (_Float16)p[0]; w[1] = (_Float16)p[1];
            w[2] = (_Float16)p[2]; w[3] = (_Float16)p[3];
#endif
            w = EMIN4(w, wcap);   // min(exp2(s),2^14) == exp2(min(s,14))
            const int jc  = c * 2 + (quad >> 1);               // 16B chunk 0..7
            const int col = ((jc ^ (row & 7)) << 3) + (quad & 1) * 4;
            *(half4v*)&Pl[(qs * 16 + row) * 64 + col] = w;
        }
    }
    // Same-wave DS ordering: ensure P writes land before the gathers below.
    asm volatile("s_waitcnt lgkmcnt(0)" ::: "memory");

    half8 af[2][SN];
#pragma unroll
    for (int qs = 0; qs < 2; ++qs)
#pragma unroll
        for (int s = 0; s < SN; ++s) {
            const int js = (s * 4 + quad) ^ (row & 7);
            af[qs][s] = *(const half8*)&Pl[(qs * 16 + row) * 64 + js * 8];
        }

    // ---- O^T += V^T * P^T  (vf reused across both q sub-tiles)
#pragma unroll
    for (int c = 0; c < 4; ++c)
#pragma unroll
        for (int s = 0; s < SN; ++s) {
            o_acc[0][c] = __builtin_amdgcn_mfma_f32_16x16x32_f16(vfr[c][s], af[0][s], o_acc[0][c], 0, 0, 0);
            o_acc[1][c] = __builtin_amdgcn_mfma_f32_16x16x32_f16(vfr[c][s], af[1][s], o_acc[1][c], 0, 0, 0);
        }
    // ---- l(q) += sum_kv P via ones-MFMA (no shuffles, no reductions)
#pragma unroll
    for (int qs = 0; qs < 2; ++qs)
#pragma unroll
        for (int s = 0; s < SN; ++s)
            lacc[qs] = __builtin_amdgcn_mfma_f32_16x16x32_f16(ones, af[qs][s], lacc[qs], 0, 0, 0);
}

// ---------------- main flash kernel: 1 wave / 64 threads per block ----------
__global__ __launch_bounds__(64, 2)
void fa_main(const float* __restrict__ Q, const _Float16* __restrict__ Kh,
             const _Float16* __restrict__ Vt, float* __restrict__ O) {
    const int bid = blockIdx.x;
    // XCD swizzle: all 32 pair-blocks of a bh on one XCD (K/V L2-resident;
    // 8 bh per XCD = 4MB = L2).
    const int xcd = bid & 7;
    const int m   = bid >> 3;          // 0..255
    const int pr  = m & 31;            // pair index: 32-row q-tiles pr and 63-pr
    const int bh  = xcd * 8 + (m >> 5);

    const float*    Qb = Q  + (size_t)bh * SEQ * DIM;
    const _Float16* Kb = Kh + (size_t)bh * SEQ * DIM;
    const _Float16* Vb = Vt + (size_t)bh * DIM * SEQ;
    float*          Ob = O  + (size_t)bh * SEQ * DIM;

    const int lane = threadIdx.x;      // 0..63 (one wave)
    const int row  = lane & 15;
    const int quad = lane >> 4;

    __shared__ _Float16 Pl[32 * 64];   // wave-private P, XOR-swizzled 16B chunks

    const float SC = 0.125f * 1.44269504f;   // 1/sqrt(D) * log2(e)
    half8 ones;
#pragma unroll
    for (int j = 0; j < 8; ++j) ones[j] = (_Float16)1.0f;

    for (int ph = 0; ph < 2; ++ph) {
        const int t    = ph ? (63 - pr) : pr;   // 32-row q-tile index 0..63
        const int q0   = t * 32;
        const int kmax = t >> 1;                // diagonal KV-tile index

        // ---- Q fragments (scale folded; log2 domain)
        half8 qf[4];   // [qs*2 + s]
#pragma unroll
        for (int qs = 0; qs < 2; ++qs) {
            const float* qp = Qb + (size_t)(q0 + qs * 16 + row) * DIM;
#pragma unroll
            for (int s = 0; s < 2; ++s) {
                const float* p = qp + s * 32 + quad * 8;
                float4v a = *(const float4v*)p;
                float4v b = *(const float4v*)(p + 4);
                half8 h;
                h[0] = (_Float16)(a[0] * SC); h[1] = (_Float16)(a[1] * SC);
                h[2] = (_Float16)(a[2] * SC); h[3] = (_Float16)(a[3] * SC);
                h[4] = (_Float16)(b[0] * SC); h[5] = (_Float16)(b[1] * SC);
                h[6] = (_Float16)(b[2] * SC); h[7] = (_Float16)(b[3] * SC);
                qf[qs * 2 + s] = h;
            }
        }

        float4v o_acc[2][4];
        float4v lacc[2];
#pragma unroll
        for (int qs = 0; qs < 2; ++qs) {
            float4v z = {0.f, 0.f, 0.f, 0.f};
            lacc[qs] = z;
#pragma unroll
            for (int c = 0; c < 4; ++c) o_acc[qs][c] = z;
        }

        // ---- mask-free main loop (no barriers anywhere)
        for (int kt = 0; kt < kmax; ++kt)
            kv_tile<4, 2, false>(Kb + (size_t)kt * 64 * DIM, Vb + kt * 64,
                                 0, 0, row, quad, qf, o_acc, lacc, Pl, ones);

        // ---- peeled diagonal tile: even t -> only kv 0..31 live
        if (t & 1)
            kv_tile<4, 2, true>(Kb + (size_t)kmax * 64 * DIM, Vb + kmax * 64,
                                kmax * 64, q0, row, quad, qf, o_acc, lacc, Pl, ones);
        else
            kv_tile<2, 1, true>(Kb + (size_t)kmax * 64 * DIM, Vb + kmax * 64,
                                kmax * 64, q0, row, quad, qf, o_acc, lacc, Pl, ones);

        // ---- epilogue: every lane holds full l(q) in lacc[qs][0]
#pragma unroll
        for (int qs = 0; qs < 2; ++qs) {
            const float inv = 1.0f / lacc[qs][0];
            float* op = Ob + (size_t)(q0 + qs * 16 + row) * DIM + quad * 4;
#pragma unroll
            for (int c = 0; c < 4; ++c) {
                float4v o;
                o[0] = o_acc[qs][c][0] * inv; o[1] = o_acc[qs][c][1] * inv;
                o[2] = o_acc[qs][c][2] * inv; o[3] = o_acc[qs][c][3] * inv;
                *(float4v*)(op + c * 16) = o;
            }
        }
    }
}

// ---------------- fallback (R1 kernel, used if ws too small) ----------------
__global__ __launch_bounds__(256)
void fa_causal_fallback(const float* __restrict__ Q, const float* __restrict__ K,
                        const float* __restrict__ V, float* __restrict__ O) {
    const int bid = blockIdx.x;
    const int bh  = bid >> 5;
    const int qt  = bid & 31;
    const int q0  = qt * 64;

    const float* Qb = Q + (size_t)bh * SEQ * DIM;
    const float* Kb = K + (size_t)bh * SEQ * DIM;
    const float* Vb = V + (size_t)bh * SEQ * DIM;
    float*       Ob = O + (size_t)bh * SEQ * DIM;

    const int tid  = threadIdx.x;
    const int wave = tid >> 6;
    const int lane = tid & 63;
    const int row  = lane & 15;
    const int quad = lane >> 4;

    __shared__ _Float16 Kl[64][72];
    __shared__ _Float16 Vt[64][72];
    __shared__ _Float16 Pl[4][16][72];

    half8 qf[2];
    {
        const float* qp = Qb + (size_t)(q0 + wave * 16 + row) * DIM;
#pragma unroll
        for (int s = 0; s < 2; ++s) {
            const float* p = qp + s * 32 + quad * 8;
            float4v a = *(const float4v*)p;
            float4v b = *(const float4v*)(p + 4);
            half8 h;
            h[0] = (_Float16)a[0]; h[1] = (_Float16)a[1];
            h[2] = (_Float16)a[2]; h[3] = (_Float16)a[3];
            h[4] = (_Float16)b[0]; h[5] = (_Float16)b[1];
            h[6] = (_Float16)b[2]; h[7] = (_Float16)b[3];
            qf[s] = h;
        }
    }

    float m_i[4] = {-1e30f, -1e30f, -1e30f, -1e30f};
    float l_i[4] = {0.f, 0.f, 0.f, 0.f};
    float4v o_acc[4];
#pragma unroll
    for (int c = 0; c < 4; ++c) { float4v z = {0.f, 0.f, 0.f, 0.f}; o_acc[c] = z; }

    const float LOG2E = 1.44269504f;

    for (int kt = 0; kt <= qt; ++kt) {
        __syncthreads();
        {
            const int kvr = tid >> 2;
            const int c4  = tid & 3;
            const float* kp = Kb + (size_t)(kt * 64 + kvr) * DIM + c4 * 16;
            const float* vp = Vb + (size_t)(kt * 64 + kvr) * DIM + c4 * 16;
#pragma unroll
            for (int i = 0; i < 4; ++i) {
                float4v kx = *(const float4v*)(kp + i * 4);
                float4v vx = *(const float4v*)(vp + i * 4);
#pragma unroll
                for (int j = 0; j < 4; ++j) {
                    Kl[kvr][c4 * 16 + i * 4 + j] = (_Float16)kx[j];
                    Vt[c4 * 16 + i * 4 + j][kvr] = (_Float16)vx[j];
                }
            }
        }
        __syncthreads();

        float4v sacc[4];
#pragma unroll
        for (int c = 0; c < 4; ++c) { float4v z = {0.f, 0.f, 0.f, 0.f}; sacc[c] = z; }
#pragma unroll
        for (int c = 0; c < 4; ++c)
#pragma unroll
            for (int s = 0; s < 2; ++s) {
                half8 kf = *(const half8*)&Kl[c * 16 + row][s * 32 + quad * 8];
                sacc[c] = __builtin_amdgcn_mfma_f32_16x16x32_f16(qf[s], kf, sacc[c], 0, 0, 0);
            }

        float sv[4][4];
        const bool diag = (kt == qt);
#pragma unroll
        for (int c = 0; c < 4; ++c)
#pragma unroll
            for (int r = 0; r < 4; ++r) {
                float v = sacc[c][r] * 0.125f;
                if (diag) {
                    int kvl = c * 16 + row;
                    int ql  = wave * 16 + quad * 4 + r;
                    if (kvl > ql) v = -1e30f;
                }
                sv[c][r] = v;
            }

        float mnew[4], alpha[4];
#pragma unroll
        for (int r = 0; r < 4; ++r) {
            float rm = fmaxf(fmaxf(sv[0][r], sv[1][r]), fmaxf(sv[2][r], sv[3][r]));
            rm = fmaxf(rm, __shfl_xor(rm, 1));
            rm = fmaxf(rm, __shfl_xor(rm, 2));
            rm = fmaxf(rm, __shfl_xor(rm, 4));
            rm = fmaxf(rm, __shfl_xor(rm, 8));
            mnew[r]  = fmaxf(m_i[r], rm);
            alpha[r] = exp2f((m_i[r] - mnew[r]) * LOG2E);
            m_i[r]   = mnew[r];
        }
        float rs[4] = {0.f, 0.f, 0.f, 0.f};
#pragma unroll
        for (int c = 0; c < 4; ++c)
#pragma unroll
            for (int r = 0; r < 4; ++r) {
                float p = exp2f((sv[c][r] - mnew[r]) * LOG2E);
                sv[c][r] = p;
                rs[r] += p;
            }
#pragma unroll
        for (int r = 0; r < 4; ++r) {
            float s = rs[r];
            s += __shfl_xor(s, 1);
            s += __shfl_xor(s, 2);
            s += __shfl_xor(s, 4);
            s += __shfl_xor(s, 8);
            l_i[r] = l_i[r] * alpha[r] + s;
        }
#pragma unroll
        for (int c = 0; c < 4; ++c)
#pragma unroll
            for (int r = 0; r < 4; ++r)
                o_acc[c][r] *= alpha[r];

#pragma unroll
        for (int c = 0; c < 4; ++c)
#pragma unroll
            for (int r = 0; r < 4; ++r)
                Pl[wave][quad * 4 + r][c * 16 + row] = (_Float16)sv[c][r];
        __syncthreads();

        half8 af[2];
#pragma unroll
        for (int s = 0; s < 2; ++s)
            af[s] = *(const half8*)&Pl[wave][row][s * 32 + quad * 8];
#pragma unroll
        for (int c = 0; c < 4; ++c)
#pragma unroll
            for (int s = 0; s < 2; ++s) {
                half8 vf = *(const half8*)&Vt[c * 16 + row][s * 32 + quad * 8];
                o_acc[c] = __builtin_amdgcn_mfma_f32_16x16x32_f16(af[s], vf, o_acc[c], 0, 0, 0);
            }
    }

#pragma unroll
    for (int r = 0; r < 4; ++r) {
        float inv = 1.0f / l_i[r];
        float* op = Ob + (size_t)(q0 + wave * 16 + quad * 4 + r) * DIM;
#pragma unroll
        for (int c = 0; c < 4; ++c)
            op[c * 16 + row] = o_acc[c][r] * inv;
    }
}

extern "C" void kernel_launch(void* const* d_in, const int* in_sizes, int n_in,
                              void* d_out, int out_size, void* d_ws, size_t ws_size,
                              hipStream_t stream) {
    const float* Q = (const float*)d_in[0];
    const float* K = (const float*)d_in[1];
    const float* V = (const float*)d_in[2];
    float* O = (float*)d_out;

    const size_t elems = (size_t)BH * SEQ * DIM;
    const size_t need  = 2 * elems * sizeof(_Float16);

    if (ws_size >= need) {
        _Float16* Kh = (_Float16*)d_ws;
        _Float16* Vt = Kh + elems;
        prep_kernel<<<4096 + 2048, 256, 0, stream>>>(K, V, Kh, Vt);
        fa_main<<<BH * 32, 64, 0, stream>>>(Q, Kh, Vt, O);
    } else {
        fa_causal_fallback<<<BH * 32, 256, 0, stream>>>(Q, K, V, O);
    }
}

// Round 4
// 210.320 us; speedup vs baseline: 1.1921x; 1.1921x over previous
//
#include <hip/hip_runtime.h>
#include <hip/hip_bf16.h>

// Causal SDPA: B=4, H=16, S=2048, D=64, fp32 in/out.
// R12 = R11 resubmit (bench infra failed twice; no counter evidence against
// the theory). Structure:
//   round(6700cyc) ~= VALU(~3000, tracks VALUBusy) + serial-chain stall(~3700)
//   (1) __builtin_amdgcn_exp2f: single v_exp_f32 instead of OCML libcall.
//   (2) Un-paired grid (2048 blocks, big-t first) + K-only LDS staging
//       (24KB/block) -> 6 independent de-phased blocks/CU (12 waves) fill
//       each other's serial-chain stalls. V fragments direct from L2
//       (XCD-pinned), issued at iteration top; K stays DMA-staged dbuf.
//   (3) s_setprio(1) around MFMA clusters; __launch_bounds__(128,3).

#define SEQ 2048
#define DIM 64
#define BH  64

typedef _Float16 half8  __attribute__((ext_vector_type(8)));
typedef _Float16 half4v __attribute__((ext_vector_type(4)));
typedef float    float4v __attribute__((ext_vector_type(4)));
typedef unsigned short ushort4v __attribute__((ext_vector_type(4)));

__device__ __forceinline__ void async16(const _Float16* g, _Float16* l) {
    __builtin_amdgcn_global_load_lds(
        (const __attribute__((address_space(1))) void*)g,
        (__attribute__((address_space(3))) void*)l, 16, 0, 0);
}

#if defined(__has_builtin)
#if __has_builtin(__builtin_elementwise_min)
#define EMIN4(a, b) __builtin_elementwise_min((a), (b))
#endif
#if __has_builtin(__builtin_amdgcn_exp2f)
#define EXP2F(x) __builtin_amdgcn_exp2f(x)
#endif
#endif
#ifndef EMIN4
__device__ __forceinline__ half4v emin4_fallback(half4v a, half4v b) {
    half4v r;
    r[0] = a[0] < b[0] ? a[0] : b[0];
    r[1] = a[1] < b[1] ? a[1] : b[1];
    r[2] = a[2] < b[2] ? a[2] : b[2];
    r[3] = a[3] < b[3] ? a[3] : b[3];
    return r;
}
#define EMIN4(a, b) emin4_fallback((a), (b))
#endif
#ifndef EXP2F
#define EXP2F(x) exp2f(x)
#endif

// ---------------- pre-pass: K convert + V transpose-convert ----------------
__global__ __launch_bounds__(256)
void prep_kernel(const float* __restrict__ K, const float* __restrict__ V,
                 _Float16* __restrict__ Kh, _Float16* __restrict__ Vt) {
    const int bid = blockIdx.x;
    const int tid = threadIdx.x;
    if (bid < 4096) {
        // K: fp32 -> f16, same layout, fully coalesced.
        size_t idx = (size_t)bid * 2048 + (size_t)tid * 8;
        float4v a = *(const float4v*)(K + idx);
        float4v b = *(const float4v*)(K + idx + 4);
        half8 h;
        h[0] = (_Float16)a[0]; h[1] = (_Float16)a[1];
        h[2] = (_Float16)a[2]; h[3] = (_Float16)a[3];
        h[4] = (_Float16)b[0]; h[5] = (_Float16)b[1];
        h[6] = (_Float16)b[2]; h[7] = (_Float16)b[3];
        *(half8*)(Kh + idx) = h;
    } else {
        // V transpose via LDS, flat [64 rows x 8 chunks of 16B].
        // Chunk c of row r stored at c ^ k(r), k(r) = (r + (r>>3)) & 7.
        __shared__ _Float16 Vl[64 * 64];
        const int b  = bid - 4096;
        const int bh = b >> 5;
        const int s0 = (b & 31) * 64;
        {
            const int r   = tid >> 2;         // s within tile
            const int c16 = (tid & 3) * 16;   // col group (d)
            const float* p = V + ((size_t)bh * SEQ + s0 + r) * DIM + c16;
            float4v x0 = *(const float4v*)(p);
            float4v x1 = *(const float4v*)(p + 4);
            float4v x2 = *(const float4v*)(p + 8);
            float4v x3 = *(const float4v*)(p + 12);
            half8 h0, h1;
            h0[0] = (_Float16)x0[0]; h0[1] = (_Float16)x0[1];
            h0[2] = (_Float16)x0[2]; h0[3] = (_Float16)x0[3];
            h0[4] = (_Float16)x1[0]; h0[5] = (_Float16)x1[1];
            h0[6] = (_Float16)x1[2]; h0[7] = (_Float16)x1[3];
            h1[0] = (_Float16)x2[0]; h1[1] = (_Float16)x2[1];
            h1[2] = (_Float16)x2[2]; h1[3] = (_Float16)x2[3];
            h1[4] = (_Float16)x3[0]; h1[5] = (_Float16)x3[1];
            h1[6] = (_Float16)x3[2]; h1[7] = (_Float16)x3[3];
            const int k  = (r + (r >> 3)) & 7;
            const int j0 = c16 >> 3;          // 0,2,4,6
            *(half8*)&Vl[r * 64 + ((j0    ) ^ k) * 8] = h0;
            *(half8*)&Vl[r * 64 + ((j0 + 1) ^ k) * 8] = h1;
        }
        __syncthreads();
        {
            const int d  = tid >> 2;          // output row (d)
            const int sc = (tid & 3) * 16;    // s chunk
            const int dh = d >> 3;            // chunk index of col d
            const int dl = d & 7;             // offset within chunk
            half8 o0, o1;
#pragma unroll
            for (int j = 0; j < 8; ++j) {
                const int s1 = sc + j;
                const int s2 = sc + 8 + j;
                o0[j] = Vl[s1 * 64 + ((dh ^ ((s1 + (s1 >> 3)) & 7)) << 3) + dl];
                o1[j] = Vl[s2 * 64 + ((dh ^ ((s2 + (s2 >> 3)) & 7)) << 3) + dl];
            }
            _Float16* op = Vt + ((size_t)bh * DIM + d) * SEQ + s0 + sc;
            *(half8*)op       = o0;
            *(half8*)(op + 8) = o1;
        }
    }
}

// ---------------- main flash kernel ----------------
// 128 threads = 2 waves; each wave owns 32 q rows; one 64-row q-tile / block.
__global__ __launch_bounds__(128, 3)
void fa_main(const float* __restrict__ Q, const _Float16* __restrict__ Kh,
             const _Float16* __restrict__ Vt, float* __restrict__ O) {
    const int bid = blockIdx.x;
    // XCD swizzle: all 32 blocks of a bh on one XCD (K/V L2-resident:
    // 8 bh x (256KB K + 256KB V) = 4MB = one XCD L2).
    // Big-t first (r>>3 ascending -> t descending) for tail packing.
    const int xcd = bid & 7;
    const int r   = bid >> 3;              // 0..255
    const int bh  = xcd * 8 + (r & 7);
    const int t   = 31 - (r >> 3);         // 64-row q-tile index, big first

    const float*    Qb = Q  + (size_t)bh * SEQ * DIM;
    const _Float16* Kb = Kh + (size_t)bh * SEQ * DIM;
    const _Float16* Vb = Vt + (size_t)bh * DIM * SEQ;
    float*          Ob = O  + (size_t)bh * SEQ * DIM;

    const int tid  = threadIdx.x;
    const int wave = tid >> 6;    // 0..1
    const int lane = tid & 63;
    const int row  = lane & 15;
    const int quad = lane >> 4;

    // LDS = 16K (K dbuf) + 8K (P) = 24576 B -> 6 blocks/CU, 12 waves/CU.
    __shared__ _Float16 Kl[2][64 * 64];
    __shared__ _Float16 Pl[2][32 * 64];

    const float SC = 0.125f * 1.44269504f;   // 1/sqrt(D) * log2(e)
    const float4v z0 = {0.f, 0.f, 0.f, 0.f}; // loop-invariant MFMA C operand
    half8 ones;
    {
        ushort4v ob;  // 0x3c00 = f16 1.0, bit-pattern to avoid cvt chains
        ob[0] = 0x3c00; ob[1] = 0x3c00; ob[2] = 0x3c00; ob[3] = 0x3c00;
        half4v o1 = __builtin_bit_cast(half4v, ob);
        ones[0] = o1[0]; ones[1] = o1[1]; ones[2] = o1[2]; ones[3] = o1[3];
        ones[4] = o1[0]; ones[5] = o1[1]; ones[6] = o1[2]; ones[7] = o1[3];
    }
    half4v wcap;
    {
        ushort4v cb;  // 0x7400 = f16 16384.0 = 2^14
        cb[0] = 0x7400; cb[1] = 0x7400; cb[2] = 0x7400; cb[3] = 0x7400;
        wcap = __builtin_bit_cast(half4v, cb);
    }

    // K tile = 512 x 16B chunks; wave w stages chunks w*256 .. w*256+255.
#define STAGE_K(bsel, kt_)                                                      \
    {                                                                           \
        const _Float16* Kt0 = Kb + (size_t)(kt_) * 64 * DIM;                    \
        _Pragma("unroll")                                                       \
        for (int i = 0; i < 4; ++i) {                                           \
            int pos = wave * 256 + i * 64 + lane;                               \
            int rr  = pos >> 3;                                                 \
            int cc  = (pos & 7) ^ (rr & 7);                                     \
            async16(Kt0 + (size_t)rr * DIM + cc * 8,                            \
                    &Kl[bsel][0] + (size_t)(wave * 256 + i * 64) * 8);          \
        }                                                                       \
    }

    const int q0 = t * 64;

    // ---- Q fragments (scale folded; log2 domain)
    half8 qf[4];   // [qs*2 + s]
#pragma unroll
    for (int qs = 0; qs < 2; ++qs) {
        const float* qp = Qb + (size_t)(q0 + wave * 32 + qs * 16 + row) * DIM;
#pragma unroll
        for (int s = 0; s < 2; ++s) {
            const float* p = qp + s * 32 + quad * 8;
            float4v a = *(const float4v*)p;
            float4v b = *(const float4v*)(p + 4);
            half8 h;
            h[0] = (_Float16)(a[0] * SC); h[1] = (_Float16)(a[1] * SC);
            h[2] = (_Float16)(a[2] * SC); h[3] = (_Float16)(a[3] * SC);
            h[4] = (_Float16)(b[0] * SC); h[5] = (_Float16)(b[1] * SC);
            h[6] = (_Float16)(b[2] * SC); h[7] = (_Float16)(b[3] * SC);
            qf[qs * 2 + s] = h;
        }
    }

    float4v o_acc[2][4];
    float4v lacc[2];
#pragma unroll
    for (int qs = 0; qs < 2; ++qs) {
        float4v z = {0.f, 0.f, 0.f, 0.f};
        lacc[qs] = z;
#pragma unroll
        for (int c = 0; c < 4; ++c) o_acc[qs][c] = z;
    }

    STAGE_K(0, 0)
    __syncthreads();   // drain initial DMA

    for (int kt = 0; kt <= t; ++kt) {
        const int cb = kt & 1;
        if (kt < t) STAGE_K(cb ^ 1, kt + 1)   // prefetch; drained by end barrier

        // ---- V fragments direct from L2, issued NOW (consumed ~2000cyc
        //      later in PV -> latency hidden under S^T + softmax).
        half8 vfr[4][2];
        {
            const _Float16* vp0 = Vb + (size_t)kt * 64 + quad * 8;
#pragma unroll
            for (int c = 0; c < 4; ++c) {
                const _Float16* vp = vp0 + (size_t)(c * 16 + row) * SEQ;
                vfr[c][0] = *(const half8*)(vp);
                vfr[c][1] = *(const half8*)(vp + 32);
            }
        }

        // ---- S^T = K * Q^T  (A = K rows; D: row = kv, col = q)
        float4v sacc[2][4];
        __builtin_amdgcn_s_setprio(1);
#pragma unroll
        for (int c = 0; c < 4; ++c) {
            const int kv  = c * 16 + row;
            const int ch0 = quad ^ (row & 7);         // (kv&7)==(row&7)
            const int ch1 = (4 + quad) ^ (row & 7);
            half8 kf0 = *(const half8*)&Kl[cb][kv * 64 + ch0 * 8];
            half8 kf1 = *(const half8*)&Kl[cb][kv * 64 + ch1 * 8];
#pragma unroll
            for (int qs = 0; qs < 2; ++qs) {
                float4v s0 = __builtin_amdgcn_mfma_f32_16x16x32_f16(kf0, qf[qs * 2 + 0], z0, 0, 0, 0);
                sacc[qs][c] = __builtin_amdgcn_mfma_f32_16x16x32_f16(kf1, qf[qs * 2 + 1], s0, 0, 0, 0);
            }
        }
        __builtin_amdgcn_s_setprio(0);

        // ---- exp2 (single v_exp_f32; overflow clamped post-cvt in f16),
        //      mask on diagonal tile only.
        float pv[2][4][4];
        if (kt == t) {
#pragma unroll
            for (int qs = 0; qs < 2; ++qs) {
                const int ql = wave * 32 + qs * 16 + row;
#pragma unroll
                for (int c = 0; c < 4; ++c)
#pragma unroll
                    for (int rr = 0; rr < 4; ++rr) {
                        int kvl = c * 16 + quad * 4 + rr;
                        float sx = (kvl > ql) ? -1e30f : sacc[qs][c][rr];
                        pv[qs][c][rr] = EXP2F(sx);
                    }
            }
        } else {
#pragma unroll
            for (int qs = 0; qs < 2; ++qs)
#pragma unroll
                for (int c = 0; c < 4; ++c)
#pragma unroll
                    for (int rr = 0; rr < 4; ++rr)
                        pv[qs][c][rr] = EXP2F(sacc[qs][c][rr]);
        }

        // ---- P^T -> Pl (packed cvt + f16 clamp; swizzled 16B chunks)
#pragma unroll
        for (int qs = 0; qs < 2; ++qs)
#pragma unroll
            for (int c = 0; c < 4; ++c) {
#if defined(__has_builtin) && __has_builtin(__builtin_amdgcn_cvt_pkrtz)
                auto t0 = __builtin_amdgcn_cvt_pkrtz(pv[qs][c][0], pv[qs][c][1]);
                auto t1 = __builtin_amdgcn_cvt_pkrtz(pv[qs][c][2], pv[qs][c][3]);
                half4v w;
                w[0] = t0[0]; w[1] = t0[1]; w[2] = t1[0]; w[3] = t1[1];
#else
                half4v w;
                w[0] = (_Float16)pv[qs][c][0]; w[1] = (_Float16)pv[qs][c][1];
                w[2] = (_Float16)pv[qs][c][2]; w[3] = (_Float16)pv[qs][c][3];
#endif
                w = EMIN4(w, wcap);   // min(exp2(s),2^14) == exp2(min(s,14))
                const int jc  = c * 2 + (quad >> 1);           // 16B chunk 0..7
                const int col = ((jc ^ (row & 7)) << 3) + (quad & 1) * 4;
                *(half4v*)&Pl[wave][(qs * 16 + row) * 64 + col] = w;
            }
        asm volatile("s_waitcnt lgkmcnt(0)" ::: "memory");
        half8 af[2][2];
#pragma unroll
        for (int qs = 0; qs < 2; ++qs)
#pragma unroll
            for (int s = 0; s < 2; ++s) {
                const int js = (s * 4 + quad) ^ (row & 7);
                af[qs][s] = *(const half8*)&Pl[wave][(qs * 16 + row) * 64 + js * 8];
            }

        // ---- O^T += V^T * P^T  (vfr from L2, loaded at iter top)
        __builtin_amdgcn_s_setprio(1);
#pragma unroll
        for (int c = 0; c < 4; ++c)
#pragma unroll
            for (int s = 0; s < 2; ++s) {
                o_acc[0][c] = __builtin_amdgcn_mfma_f32_16x16x32_f16(vfr[c][s], af[0][s], o_acc[0][c], 0, 0, 0);
                o_acc[1][c] = __builtin_amdgcn_mfma_f32_16x16x32_f16(vfr[c][s], af[1][s], o_acc[1][c], 0, 0, 0);
            }
        // ---- l(q) += sum_kv P via ones-MFMA
#pragma unroll
        for (int qs = 0; qs < 2; ++qs)
#pragma unroll
            for (int s = 0; s < 2; ++s)
                lacc[qs] = __builtin_amdgcn_mfma_f32_16x16x32_f16(ones, af[qs][s], lacc[qs], 0, 0, 0);
        __builtin_amdgcn_s_setprio(0);

        __syncthreads();   // separates K reads from next overwrite; drains prefetch
    }

    // ---- epilogue: every lane holds full l(q) in lacc[qs][0]
#pragma unroll
    for (int qs = 0; qs < 2; ++qs) {
        const float inv = 1.0f / lacc[qs][0];
        float* op = Ob + (size_t)(q0 + wave * 32 + qs * 16 + row) * DIM + quad * 4;
#pragma unroll
        for (int c = 0; c < 4; ++c) {
            float4v o;
            o[0] = o_acc[qs][c][0] * inv; o[1] = o_acc[qs][c][1] * inv;
            o[2] = o_acc[qs][c][2] * inv; o[3] = o_acc[qs][c][3] * inv;
            *(float4v*)(op + c * 16) = o;
        }
    }
}

// ---------------- fallback (R1 kernel, used if ws too small) ----------------
__global__ __launch_bounds__(256)
void fa_causal_fallback(const float* __restrict__ Q, const float* __restrict__ K,
                        const float* __restrict__ V, float* __restrict__ O) {
    const int bid = blockIdx.x;
    const int bh  = bid >> 5;
    const int qt  = bid & 31;
    const int q0  = qt * 64;

    const float* Qb = Q + (size_t)bh * SEQ * DIM;
    const float* Kb = K + (size_t)bh * SEQ * DIM;
    const float* Vb = V + (size_t)bh * SEQ * DIM;
    float*       Ob = O + (size_t)bh * SEQ * DIM;

    const int tid  = threadIdx.x;
    const int wave = tid >> 6;
    const int lane = tid & 63;
    const int row  = lane & 15;
    const int quad = lane >> 4;

    __shared__ _Float16 Kl[64][72];
    __shared__ _Float16 Vt[64][72];
    __shared__ _Float16 Pl[4][16][72];

    half8 qf[2];
    {
        const float* qp = Qb + (size_t)(q0 + wave * 16 + row) * DIM;
#pragma unroll
        for (int s = 0; s < 2; ++s) {
            const float* p = qp + s * 32 + quad * 8;
            float4v a = *(const float4v*)p;
            float4v b = *(const float4v*)(p + 4);
            half8 h;
            h[0] = (_Float16)a[0]; h[1] = (_Float16)a[1];
            h[2] = (_Float16)a[2]; h[3] = (_Float16)a[3];
            h[4] = (_Float16)b[0]; h[5] = (_Float16)b[1];
            h[6] = (_Float16)b[2]; h[7] = (_Float16)b[3];
            qf[s] = h;
        }
    }

    float m_i[4] = {-1e30f, -1e30f, -1e30f, -1e30f};
    float l_i[4] = {0.f, 0.f, 0.f, 0.f};
    float4v o_acc[4];
#pragma unroll
    for (int c = 0; c < 4; ++c) { float4v z = {0.f, 0.f, 0.f, 0.f}; o_acc[c] = z; }

    const float LOG2E = 1.44269504f;

    for (int kt = 0; kt <= qt; ++kt) {
        __syncthreads();
        {
            const int kvr = tid >> 2;
            const int c4  = tid & 3;
            const float* kp = Kb + (size_t)(kt * 64 + kvr) * DIM + c4 * 16;
            const float* vp = Vb + (size_t)(kt * 64 + kvr) * DIM + c4 * 16;
#pragma unroll
            for (int i = 0; i < 4; ++i) {
                float4v kx = *(const float4v*)(kp + i * 4);
                float4v vx = *(const float4v*)(vp + i * 4);
#pragma unroll
                for (int j = 0; j < 4; ++j) {
                    Kl[kvr][c4 * 16 + i * 4 + j] = (_Float16)kx[j];
                    Vt[c4 * 16 + i * 4 + j][kvr] = (_Float16)vx[j];
                }
            }
        }
        __syncthreads();

        float4v sacc[4];
#pragma unroll
        for (int c = 0; c < 4; ++c) { float4v z = {0.f, 0.f, 0.f, 0.f}; sacc[c] = z; }
#pragma unroll
        for (int c = 0; c < 4; ++c)
#pragma unroll
            for (int s = 0; s < 2; ++s) {
                half8 kf = *(const half8*)&Kl[c * 16 + row][s * 32 + quad * 8];
                sacc[c] = __builtin_amdgcn_mfma_f32_16x16x32_f16(qf[s], kf, sacc[c], 0, 0, 0);
            }

        float sv[4][4];
        const bool diag = (kt == qt);
#pragma unroll
        for (int c = 0; c < 4; ++c)
#pragma unroll
            for (int r = 0; r < 4; ++r) {
                float v = sacc[c][r] * 0.125f;
                if (diag) {
                    int kvl = c * 16 + row;
                    int ql  = wave * 16 + quad * 4 + r;
                    if (kvl > ql) v = -1e30f;
                }
                sv[c][r] = v;
            }

        float mnew[4], alpha[4];
#pragma unroll
        for (int r = 0; r < 4; ++r) {
            float rm = fmaxf(fmaxf(sv[0][r], sv[1][r]), fmaxf(sv[2][r], sv[3][r]));
            rm = fmaxf(rm, __shfl_xor(rm, 1));
            rm = fmaxf(rm, __shfl_xor(rm, 2));
            rm = fmaxf(rm, __shfl_xor(rm, 4));
            rm = fmaxf(rm, __shfl_xor(rm, 8));
            mnew[r]  = fmaxf(m_i[r], rm);
            alpha[r] = exp2f((m_i[r] - mnew[r]) * LOG2E);
            m_i[r]   = mnew[r];
        }
        float rs[4] = {0.f, 0.f, 0.f, 0.f};
#pragma unroll
        for (int c = 0; c < 4; ++c)
#pragma unroll
            for (int r = 0; r < 4; ++r) {
                float p = exp2f((sv[c][r] - mnew[r]) * LOG2E);
                sv[c][r] = p;
                rs[r] += p;
            }
#pragma unroll
        for (int r = 0; r < 4; ++r) {
            float s = rs[r];
            s += __shfl_xor(s, 1);
            s += __shfl_xor(s, 2);
            s += __shfl_xor(s, 4);
            s += __shfl_xor(s, 8);
            l_i[r] = l_i[r] * alpha[r] + s;
        }
#pragma unroll
        for (int c = 0; c < 4; ++c)
#pragma unroll
            for (int r = 0; r < 4; ++r)
                o_acc[c][r] *= alpha[r];

#pragma unroll
        for (int c = 0; c < 4; ++c)
#pragma unroll
            for (int r = 0; r < 4; ++r)
                Pl[wave][quad * 4 + r][c * 16 + row] = (_Float16)sv[c][r];
        __syncthreads();

        half8 af[2];
#pragma unroll
        for (int s = 0; s < 2; ++s)
            af[s] = *(const half8*)&Pl[wave][row][s * 32 + quad * 8];
#pragma unroll
        for (int c = 0; c < 4; ++c)
#pragma unroll
            for (int s = 0; s < 2; ++s) {
                half8 vf = *(const half8*)&Vt[c * 16 + row][s * 32 + quad * 8];
                o_acc[c] = __builtin_amdgcn_mfma_f32_16x16x32_f16(af[s], vf, o_acc[c], 0, 0, 0);
            }
    }

#pragma unroll
    for (int r = 0; r < 4; ++r) {
        float inv = 1.0f / l_i[r];
        float* op = Ob + (size_t)(q0 + wave * 16 + quad * 4 + r) * DIM;
#pragma unroll
        for (int c = 0; c < 4; ++c)
            op[c * 16 + row] = o_acc[c][r] * inv;
    }
}

extern "C" void kernel_launch(void* const* d_in, const int* in_sizes, int n_in,
                              void* d_out, int out_size, void* d_ws, size_t ws_size,
                              hipStream_t stream) {
    const float* Q = (const float*)d_in[0];
    const float* K = (const float*)d_in[1];
    const float* V = (const float*)d_in[2];
    float* O = (float*)d_out;

    const size_t elems = (size_t)BH * SEQ * DIM;
    const size_t need  = 2 * elems * sizeof(_Float16);

    if (ws_size >= need) {
        _Float16* Kh = (_Float16*)d_ws;
        _Float16* Vt = Kh + elems;
        prep_kernel<<<4096 + 2048, 256, 0, stream>>>(K, V, Kh, Vt);
        fa_main<<<BH * 32, 128, 0, stream>>>(Q, Kh, Vt, O);
    } else {
        fa_causal_fallback<<<BH * 32, 256, 0, stream>>>(Q, K, V, O);
    }
}

// Round 5
// 184.693 us; speedup vs baseline: 1.3575x; 1.1388x over previous
//
#include <hip/hip_runtime.h>
#include <hip/hip_bf16.h>

// Causal SDPA: B=4, H=16, S=2048, D=64, fp32 in/out.
// R13: evidence from R8/R9/R12 => slot = L/W (latency-bound, near-perfect
// cross-wave overlap; no pipe >55%). Attack W: V staging goes SINGLE-buffered
// (issued at iter top, drained by counted vmcnt(4) + raw s_barrier just before
// PV, so the 4 K-prefetch DMAs stay in flight across the barrier). LDS
// 40K -> 32K => 5 blocks/CU, W = 2.5 (+25%). Keeps: R9 math, exp2 builtin,
// V in LDS (fixes R12's FETCH regression), un-paired big-t-first 2048-block
// grid (backfill smooths causal imbalance), setprio clusters.

#define SEQ 2048
#define DIM 64
#define BH  64

typedef _Float16 half8  __attribute__((ext_vector_type(8)));
typedef _Float16 half4v __attribute__((ext_vector_type(4)));
typedef float    float4v __attribute__((ext_vector_type(4)));
typedef unsigned short ushort4v __attribute__((ext_vector_type(4)));

__device__ __forceinline__ void async16(const _Float16* g, _Float16* l) {
    __builtin_amdgcn_global_load_lds(
        (const __attribute__((address_space(1))) void*)g,
        (__attribute__((address_space(3))) void*)l, 16, 0, 0);
}

#if defined(__has_builtin)
#if __has_builtin(__builtin_elementwise_min)
#define EMIN4(a, b) __builtin_elementwise_min((a), (b))
#endif
#if __has_builtin(__builtin_amdgcn_exp2f)
#define EXP2F(x) __builtin_amdgcn_exp2f(x)
#endif
#endif
#ifndef EMIN4
__device__ __forceinline__ half4v emin4_fallback(half4v a, half4v b) {
    half4v r;
    r[0] = a[0] < b[0] ? a[0] : b[0];
    r[1] = a[1] < b[1] ? a[1] : b[1];
    r[2] = a[2] < b[2] ? a[2] : b[2];
    r[3] = a[3] < b[3] ? a[3] : b[3];
    return r;
}
#define EMIN4(a, b) emin4_fallback((a), (b))
#endif
#ifndef EXP2F
#define EXP2F(x) exp2f(x)
#endif

// ---------------- pre-pass: K convert + V transpose-convert ----------------
__global__ __launch_bounds__(256)
void prep_kernel(const float* __restrict__ K, const float* __restrict__ V,
                 _Float16* __restrict__ Kh, _Float16* __restrict__ Vt) {
    const int bid = blockIdx.x;
    const int tid = threadIdx.x;
    if (bid < 4096) {
        // K: fp32 -> f16, same layout, fully coalesced.
        size_t idx = (size_t)bid * 2048 + (size_t)tid * 8;
        float4v a = *(const float4v*)(K + idx);
        float4v b = *(const float4v*)(K + idx + 4);
        half8 h;
        h[0] = (_Float16)a[0]; h[1] = (_Float16)a[1];
        h[2] = (_Float16)a[2]; h[3] = (_Float16)a[3];
        h[4] = (_Float16)b[0]; h[5] = (_Float16)b[1];
        h[6] = (_Float16)b[2]; h[7] = (_Float16)b[3];
        *(half8*)(Kh + idx) = h;
    } else {
        // V transpose via LDS, flat [64 rows x 8 chunks of 16B].
        // Chunk c of row r stored at c ^ k(r), k(r) = (r + (r>>3)) & 7.
        __shared__ _Float16 Vl[64 * 64];
        const int b  = bid - 4096;
        const int bh = b >> 5;
        const int s0 = (b & 31) * 64;
        {
            const int r   = tid >> 2;         // s within tile
            const int c16 = (tid & 3) * 16;   // col group (d)
            const float* p = V + ((size_t)bh * SEQ + s0 + r) * DIM + c16;
            float4v x0 = *(const float4v*)(p);
            float4v x1 = *(const float4v*)(p + 4);
            float4v x2 = *(const float4v*)(p + 8);
            float4v x3 = *(const float4v*)(p + 12);
            half8 h0, h1;
            h0[0] = (_Float16)x0[0]; h0[1] = (_Float16)x0[1];
            h0[2] = (_Float16)x0[2]; h0[3] = (_Float16)x0[3];
            h0[4] = (_Float16)x1[0]; h0[5] = (_Float16)x1[1];
            h0[6] = (_Float16)x1[2]; h0[7] = (_Float16)x1[3];
            h1[0] = (_Float16)x2[0]; h1[1] = (_Float16)x2[1];
            h1[2] = (_Float16)x2[2]; h1[3] = (_Float16)x2[3];
            h1[4] = (_Float16)x3[0]; h1[5] = (_Float16)x3[1];
            h1[6] = (_Float16)x3[2]; h1[7] = (_Float16)x3[3];
            const int k  = (r + (r >> 3)) & 7;
            const int j0 = c16 >> 3;          // 0,2,4,6
            *(half8*)&Vl[r * 64 + ((j0    ) ^ k) * 8] = h0;
            *(half8*)&Vl[r * 64 + ((j0 + 1) ^ k) * 8] = h1;
        }
        __syncthreads();
        {
            const int d  = tid >> 2;          // output row (d)
            const int sc = (tid & 3) * 16;    // s chunk
            const int dh = d >> 3;            // chunk index of col d
            const int dl = d & 7;             // offset within chunk
            half8 o0, o1;
#pragma unroll
            for (int j = 0; j < 8; ++j) {
                const int s1 = sc + j;
                const int s2 = sc + 8 + j;
                o0[j] = Vl[s1 * 64 + ((dh ^ ((s1 + (s1 >> 3)) & 7)) << 3) + dl];
                o1[j] = Vl[s2 * 64 + ((dh ^ ((s2 + (s2 >> 3)) & 7)) << 3) + dl];
            }
            _Float16* op = Vt + ((size_t)bh * DIM + d) * SEQ + s0 + sc;
            *(half8*)op       = o0;
            *(half8*)(op + 8) = o1;
        }
    }
}

// ---------------- main flash kernel ----------------
// 128 threads = 2 waves; each wave owns 32 q rows; one 64-row q-tile / block.
__global__ __launch_bounds__(128, 2)
void fa_main(const float* __restrict__ Q, const _Float16* __restrict__ Kh,
             const _Float16* __restrict__ Vt, float* __restrict__ O) {
    const int bid = blockIdx.x;
    // XCD swizzle: all 32 blocks of a bh on one XCD (K/V L2-resident:
    // 8 bh x 512KB = 4MB = one XCD L2). Big-t first for backfill packing.
    const int xcd = bid & 7;
    const int idx = bid >> 3;              // 0..255
    const int bh  = xcd * 8 + (idx & 7);
    const int t   = 31 - (idx >> 3);       // 64-row q-tile index, big first

    const float*    Qb = Q  + (size_t)bh * SEQ * DIM;
    const _Float16* Kb = Kh + (size_t)bh * SEQ * DIM;
    const _Float16* Vb = Vt + (size_t)bh * DIM * SEQ;
    float*          Ob = O  + (size_t)bh * SEQ * DIM;

    const int tid  = threadIdx.x;
    const int wave = tid >> 6;    // 0..1
    const int lane = tid & 63;
    const int row  = lane & 15;
    const int quad = lane >> 4;

    // LDS = 16K (K dbuf) + 8K (V single) + 8K (P) = 32768 B -> 5 blocks/CU.
    __shared__ _Float16 Kl[2][64 * 64];
    __shared__ _Float16 Vl[64 * 64];
    __shared__ _Float16 Pl[2][32 * 64];

    const float SC = 0.125f * 1.44269504f;   // 1/sqrt(D) * log2(e)
    const float4v z0 = {0.f, 0.f, 0.f, 0.f}; // loop-invariant MFMA C operand
    half8 ones;
    {
        ushort4v ob;  // 0x3c00 = f16 1.0
        ob[0] = 0x3c00; ob[1] = 0x3c00; ob[2] = 0x3c00; ob[3] = 0x3c00;
        half4v o1 = __builtin_bit_cast(half4v, ob);
        ones[0] = o1[0]; ones[1] = o1[1]; ones[2] = o1[2]; ones[3] = o1[3];
        ones[4] = o1[0]; ones[5] = o1[1]; ones[6] = o1[2]; ones[7] = o1[3];
    }
    half4v wcap;
    {
        ushort4v cb2;  // 0x7400 = f16 16384.0 = 2^14
        cb2[0] = 0x7400; cb2[1] = 0x7400; cb2[2] = 0x7400; cb2[3] = 0x7400;
        wcap = __builtin_bit_cast(half4v, cb2);
    }

    // K tile = 512 x 16B chunks; wave w stages chunks w*256 .. w*256+255.
#define STAGE_K(bsel, kt_)                                                      \
    {                                                                           \
        const _Float16* Kt0 = Kb + (size_t)(kt_) * 64 * DIM;                    \
        _Pragma("unroll")                                                       \
        for (int i = 0; i < 4; ++i) {                                           \
            int pos = wave * 256 + i * 64 + lane;                               \
            int rr  = pos >> 3;                                                 \
            int cc  = (pos & 7) ^ (rr & 7);                                     \
            async16(Kt0 + (size_t)rr * DIM + cc * 8,                            \
                    &Kl[bsel][0] + (size_t)(wave * 256 + i * 64) * 8);          \
        }                                                                       \
    }
    // V tile (V^T rows d, stride SEQ) into the single Vl buffer.
#define STAGE_V(kt_)                                                            \
    {                                                                           \
        const _Float16* Vt0 = Vb + (size_t)(kt_) * 64;                          \
        _Pragma("unroll")                                                       \
        for (int i = 0; i < 4; ++i) {                                           \
            int pos = wave * 256 + i * 64 + lane;                               \
            int rr  = pos >> 3;                                                 \
            int cc  = (pos & 7) ^ (rr & 7);                                     \
            async16(Vt0 + (size_t)rr * SEQ + cc * 8,                            \
                    &Vl[0] + (size_t)(wave * 256 + i * 64) * 8);                \
        }                                                                       \
    }

    const int q0 = t * 64;

    // ---- Q fragments (scale folded; log2 domain)
    half8 qf[4];   // [qs*2 + s]
#pragma unroll
    for (int qs = 0; qs < 2; ++qs) {
        const float* qp = Qb + (size_t)(q0 + wave * 32 + qs * 16 + row) * DIM;
#pragma unroll
        for (int s = 0; s < 2; ++s) {
            const float* p = qp + s * 32 + quad * 8;
            float4v a = *(const float4v*)p;
            float4v b = *(const float4v*)(p + 4);
            half8 h;
            h[0] = (_Float16)(a[0] * SC); h[1] = (_Float16)(a[1] * SC);
            h[2] = (_Float16)(a[2] * SC); h[3] = (_Float16)(a[3] * SC);
            h[4] = (_Float16)(b[0] * SC); h[5] = (_Float16)(b[1] * SC);
            h[6] = (_Float16)(b[2] * SC); h[7] = (_Float16)(b[3] * SC);
            qf[qs * 2 + s] = h;
        }
    }

    float4v o_acc[2][4];
    float4v lacc[2];
#pragma unroll
    for (int qs = 0; qs < 2; ++qs) {
        float4v z = {0.f, 0.f, 0.f, 0.f};
        lacc[qs] = z;
#pragma unroll
        for (int c = 0; c < 4; ++c) o_acc[qs][c] = z;
    }

    STAGE_K(0, 0)
    __syncthreads();   // drain initial K DMA

    for (int kt = 0; kt <= t; ++kt) {
        const int cb = kt & 1;
        // V(kt) into single buffer: prior barrier guarantees all waves are
        // done reading V(kt-1). Issue V FIRST (oldest in vmcnt FIFO), then
        // the K(kt+1) prefetch; vmcnt(4) later drains V, keeps K in flight.
        STAGE_V(kt)
        if (kt < t) STAGE_K(cb ^ 1, kt + 1)

        // ---- S^T = K * Q^T  (A = K rows; D: row = kv, col = q)
        float4v sacc[2][4];
        __builtin_amdgcn_s_setprio(1);
#pragma unroll
        for (int c = 0; c < 4; ++c) {
            const int kv  = c * 16 + row;
            const int ch0 = quad ^ (row & 7);         // (kv&7)==(row&7)
            const int ch1 = (4 + quad) ^ (row & 7);
            half8 kf0 = *(const half8*)&Kl[cb][kv * 64 + ch0 * 8];
            half8 kf1 = *(const half8*)&Kl[cb][kv * 64 + ch1 * 8];
#pragma unroll
            for (int qs = 0; qs < 2; ++qs) {
                float4v s0 = __builtin_amdgcn_mfma_f32_16x16x32_f16(kf0, qf[qs * 2 + 0], z0, 0, 0, 0);
                sacc[qs][c] = __builtin_amdgcn_mfma_f32_16x16x32_f16(kf1, qf[qs * 2 + 1], s0, 0, 0, 0);
            }
        }
        __builtin_amdgcn_s_setprio(0);

        // ---- exp2 (single v_exp_f32), mask on diagonal tile only
        float pv[2][4][4];
        if (kt == t) {
#pragma unroll
            for (int qs = 0; qs < 2; ++qs) {
                const int ql = wave * 32 + qs * 16 + row;
#pragma unroll
                for (int c = 0; c < 4; ++c)
#pragma unroll
                    for (int rr = 0; rr < 4; ++rr) {
                        int kvl = c * 16 + quad * 4 + rr;
                        float sx = (kvl > ql) ? -1e30f : sacc[qs][c][rr];
                        pv[qs][c][rr] = EXP2F(sx);
                    }
            }
        } else {
#pragma unroll
            for (int qs = 0; qs < 2; ++qs)
#pragma unroll
                for (int c = 0; c < 4; ++c)
#pragma unroll
                    for (int rr = 0; rr < 4; ++rr)
                        pv[qs][c][rr] = EXP2F(sacc[qs][c][rr]);
        }

        // ---- P^T -> Pl (packed cvt + f16 clamp; swizzled 16B chunks)
#pragma unroll
        for (int qs = 0; qs < 2; ++qs)
#pragma unroll
            for (int c = 0; c < 4; ++c) {
#if defined(__has_builtin) && __has_builtin(__builtin_amdgcn_cvt_pkrtz)
                auto t0 = __builtin_amdgcn_cvt_pkrtz(pv[qs][c][0], pv[qs][c][1]);
                auto t1 = __builtin_amdgcn_cvt_pkrtz(pv[qs][c][2], pv[qs][c][3]);
                half4v w;
                w[0] = t0[0]; w[1] = t0[1]; w[2] = t1[0]; w[3] = t1[1];
#else
                half4v w;
                w[0] = (_Float16)pv[qs][c][0]; w[1] = (_Float16)pv[qs][c][1];
                w[2] = (_Float16)pv[qs][c][2]; w[3] = (_Float16)pv[qs][c][3];
#endif
                w = EMIN4(w, wcap);   // min(exp2(s),2^14) == exp2(min(s,14))
                const int jc  = c * 2 + (quad >> 1);           // 16B chunk 0..7
                const int col = ((jc ^ (row & 7)) << 3) + (quad & 1) * 4;
                *(half4v*)&Pl[wave][(qs * 16 + row) * 64 + col] = w;
            }
        asm volatile("s_waitcnt lgkmcnt(0)" ::: "memory");
        half8 af[2][2];
#pragma unroll
        for (int qs = 0; qs < 2; ++qs)
#pragma unroll
            for (int s = 0; s < 2; ++s) {
                const int js = (s * 4 + quad) ^ (row & 7);
                af[qs][s] = *(const half8*)&Pl[wave][(qs * 16 + row) * 64 + js * 8];
            }

        // ---- V barrier: drain own V DMAs (keep K prefetch in flight),
        //      then raw s_barrier so ALL waves' V writes are visible.
        if (kt < t) {
            asm volatile("s_waitcnt vmcnt(4)" ::: "memory");
        } else {
            asm volatile("s_waitcnt vmcnt(0)" ::: "memory");
        }
        __builtin_amdgcn_s_barrier();
        __builtin_amdgcn_sched_barrier(0);

        // ---- O^T += V^T * P^T
        __builtin_amdgcn_s_setprio(1);
#pragma unroll
        for (int c = 0; c < 4; ++c) {
            const int d = c * 16 + row;
#pragma unroll
            for (int s = 0; s < 2; ++s) {
                const int ch = (s * 4 + quad) ^ (row & 7);     // (d&7)==(row&7)
                half8 vf = *(const half8*)&Vl[d * 64 + ch * 8];
                o_acc[0][c] = __builtin_amdgcn_mfma_f32_16x16x32_f16(vf, af[0][s], o_acc[0][c], 0, 0, 0);
                o_acc[1][c] = __builtin_amdgcn_mfma_f32_16x16x32_f16(vf, af[1][s], o_acc[1][c], 0, 0, 0);
            }
        }
        // ---- l(q) += sum_kv P via ones-MFMA
#pragma unroll
        for (int qs = 0; qs < 2; ++qs)
#pragma unroll
            for (int s = 0; s < 2; ++s)
                lacc[qs] = __builtin_amdgcn_mfma_f32_16x16x32_f16(ones, af[qs][s], lacc[qs], 0, 0, 0);
        __builtin_amdgcn_s_setprio(0);

        // End barrier: all waves done reading Vl (next iter overwrites it)
        // and Kl[cb^1] DMA drained (vmcnt 0) for next S^T.
        __syncthreads();
    }

    // ---- epilogue: every lane holds full l(q) in lacc[qs][0]
#pragma unroll
    for (int qs = 0; qs < 2; ++qs) {
        const float inv = 1.0f / lacc[qs][0];
        float* op = Ob + (size_t)(q0 + wave * 32 + qs * 16 + row) * DIM + quad * 4;
#pragma unroll
        for (int c = 0; c < 4; ++c) {
            float4v o;
            o[0] = o_acc[qs][c][0] * inv; o[1] = o_acc[qs][c][1] * inv;
            o[2] = o_acc[qs][c][2] * inv; o[3] = o_acc[qs][c][3] * inv;
            *(float4v*)(op + c * 16) = o;
        }
    }
}

// ---------------- fallback (R1 kernel, used if ws too small) ----------------
__global__ __launch_bounds__(256)
void fa_causal_fallback(const float* __restrict__ Q, const float* __restrict__ K,
                        const float* __restrict__ V, float* __restrict__ O) {
    const int bid = blockIdx.x;
    const int bh  = bid >> 5;
    const int qt  = bid & 31;
    const int q0  = qt * 64;

    const float* Qb = Q + (size_t)bh * SEQ * DIM;
    const float* Kb = K + (size_t)bh * SEQ * DIM;
    const float* Vb = V + (size_t)bh * SEQ * DIM;
    float*       Ob = O + (size_t)bh * SEQ * DIM;

    const int tid  = threadIdx.x;
    const int wave = tid >> 6;
    const int lane = tid & 63;
    const int row  = lane & 15;
    const int quad = lane >> 4;

    __shared__ _Float16 Kl[64][72];
    __shared__ _Float16 Vt[64][72];
    __shared__ _Float16 Pl[4][16][72];

    half8 qf[2];
    {
        const float* qp = Qb + (size_t)(q0 + wave * 16 + row) * DIM;
#pragma unroll
        for (int s = 0; s < 2; ++s) {
            const float* p = qp + s * 32 + quad * 8;
            float4v a = *(const float4v*)p;
            float4v b = *(const float4v*)(p + 4);
            half8 h;
            h[0] = (_Float16)a[0]; h[1] = (_Float16)a[1];
            h[2] = (_Float16)a[2]; h[3] = (_Float16)a[3];
            h[4] = (_Float16)b[0]; h[5] = (_Float16)b[1];
            h[6] = (_Float16)b[2]; h[7] = (_Float16)b[3];
            qf[s] = h;
        }
    }

    float m_i[4] = {-1e30f, -1e30f, -1e30f, -1e30f};
    float l_i[4] = {0.f, 0.f, 0.f, 0.f};
    float4v o_acc[4];
#pragma unroll
    for (int c = 0; c < 4; ++c) { float4v z = {0.f, 0.f, 0.f, 0.f}; o_acc[c] = z; }

    const float LOG2E = 1.44269504f;

    for (int kt = 0; kt <= qt; ++kt) {
        __syncthreads();
        {
            const int kvr = tid >> 2;
            const int c4  = tid & 3;
            const float* kp = Kb + (size_t)(kt * 64 + kvr) * DIM + c4 * 16;
            const float* vp = Vb + (size_t)(kt * 64 + kvr) * DIM + c4 * 16;
#pragma unroll
            for (int i = 0; i < 4; ++i) {
                float4v kx = *(const float4v*)(kp + i * 4);
                float4v vx = *(const float4v*)(vp + i * 4);
#pragma unroll
                for (int j = 0; j < 4; ++j) {
                    Kl[kvr][c4 * 16 + i * 4 + j] = (_Float16)kx[j];
                    Vt[c4 * 16 + i * 4 + j][kvr] = (_Float16)vx[j];
                }
            }
        }
        __syncthreads();

        float4v sacc[4];
#pragma unroll
        for (int c = 0; c < 4; ++c) { float4v z = {0.f, 0.f, 0.f, 0.f}; sacc[c] = z; }
#pragma unroll
        for (int c = 0; c < 4; ++c)
#pragma unroll
            for (int s = 0; s < 2; ++s) {
                half8 kf = *(const half8*)&Kl[c * 16 + row][s * 32 + quad * 8];
                sacc[c] = __builtin_amdgcn_mfma_f32_16x16x32_f16(qf[s], kf, sacc[c], 0, 0, 0);
            }

        float sv[4][4];
        const bool diag = (kt == qt);
#pragma unroll
        for (int c = 0; c < 4; ++c)
#pragma unroll
            for (int r = 0; r < 4; ++r) {
                float v = sacc[c][r] * 0.125f;
                if (diag) {
                    int kvl = c * 16 + row;
                    int ql  = wave * 16 + quad * 4 + r;
                    if (kvl > ql) v = -1e30f;
                }
                sv[c][r] = v;
            }

        float mnew[4], alpha[4];
#pragma unroll
        for (int r = 0; r < 4; ++r) {
            float rm = fmaxf(fmaxf(sv[0][r], sv[1][r]), fmaxf(sv[2][r], sv[3][r]));
            rm = fmaxf(rm, __shfl_xor(rm, 1));
            rm = fmaxf(rm, __shfl_xor(rm, 2));
            rm = fmaxf(rm, __shfl_xor(rm, 4));
            rm = fmaxf(rm, __shfl_xor(rm, 8));
            mnew[r]  = fmaxf(m_i[r], rm);
            alpha[r] = exp2f((m_i[r] - mnew[r]) * LOG2E);
            m_i[r]   = mnew[r];
        }
        float rs[4] = {0.f, 0.f, 0.f, 0.f};
#pragma unroll
        for (int c = 0; c < 4; ++c)
#pragma unroll
            for (int r = 0; r < 4; ++r) {
                float p = exp2f((sv[c][r] - mnew[r]) * LOG2E);
                sv[c][r] = p;
                rs[r] += p;
            }
#pragma unroll
        for (int r = 0; r < 4; ++r) {
            float s = rs[r];
            s += __shfl_xor(s, 1);
            s += __shfl_xor(s, 2);
            s += __shfl_xor(s, 4);
            s += __shfl_xor(s, 8);
            l_i[r] = l_i[r] * alpha[r] + s;
        }
#pragma unroll
        for (int c = 0; c < 4; ++c)
#pragma unroll
            for (int r = 0; r < 4; ++r)
                o_acc[c][r] *= alpha[r];

#pragma unroll
        for (int c = 0; c < 4; ++c)
#pragma unroll
            for (int r = 0; r < 4; ++r)
                Pl[wave][quad * 4 + r][c * 16 + row] = (_Float16)sv[c][r];
        __syncthreads();

        half8 af[2];
#pragma unroll
        for (int s = 0; s < 2; ++s)
            af[s] = *(const half8*)&Pl[wave][row][s * 32 + quad * 8];
#pragma unroll
        for (int c = 0; c < 4; ++c)
#pragma unroll
            for (int s = 0; s < 2; ++s) {
                half8 vf = *(const half8*)&Vt[c * 16 + row][s * 32 + quad * 8];
                o_acc[c] = __builtin_amdgcn_mfma_f32_16x16x32_f16(af[s], vf, o_acc[c], 0, 0, 0);
            }
    }

#pragma unroll
    for (int r = 0; r < 4; ++r) {
        float inv = 1.0f / l_i[r];
        float* op = Ob + (size_t)(q0 + wave * 16 + quad * 4 + r) * DIM;
#pragma unroll
        for (int c = 0; c < 4; ++c)
            op[c * 16 + row] = o_acc[c][r] * inv;
    }
}

extern "C" void kernel_launch(void* const* d_in, const int* in_sizes, int n_in,
                              void* d_out, int out_size, void* d_ws, size_t ws_size,
                              hipStream_t stream) {
    const float* Q = (const float*)d_in[0];
    const float* K = (const float*)d_in[1];
    const float* V = (const float*)d_in[2];
    float* O = (float*)d_out;

    const size_t elems = (size_t)BH * SEQ * DIM;
    const size_t need  = 2 * elems * sizeof(_Float16);

    if (ws_size >= need) {
        _Float16* Kh = (_Float16*)d_ws;
        _Float16* Vt = Kh + elems;
        prep_kernel<<<4096 + 2048, 256, 0, stream>>>(K, V, Kh, Vt);
        fa_main<<<BH * 32, 128, 0, stream>>>(Q, Kh, Vt, O);
    } else {
        fa_causal_fallback<<<BH * 32, 256, 0, stream>>>(Q, K, V, O);
    }
}